// Round 8
// baseline (670.208 us; speedup 1.0000x reference)
//
#include <hip/hip_runtime.h>
#include <hip/hip_bf16.h>
#include <math.h>

typedef __hip_bfloat16 bf16;
typedef __attribute__((ext_vector_type(8))) short short8;   // 8 bf16 (4 VGPRs) MFMA A/B frag
typedef __attribute__((ext_vector_type(4))) float f32x4;    // MFMA C/D frag

#define BATCH_N 4
#define SEQ_N 4096
#define DMODEL 1024
#define DINNER 2048
#define DTRANK 64
#define DSTATE 16
#define NROWS (BATCH_N * SEQ_N)   // 16384

__device__ __forceinline__ float b2f(bf16 v) { return __bfloat162float(v); }
__device__ __forceinline__ bf16 f2b(float v) { return __float2bfloat16(v); }

// async global->LDS, 16B per lane. ldsbase must be wave-uniform; HW adds lane*16.
__device__ __forceinline__ void gll16(const bf16* g, bf16* l) {
    __builtin_amdgcn_global_load_lds((const __attribute__((address_space(1))) unsigned int*)g,
                                     (__attribute__((address_space(3))) unsigned int*)l,
                                     16, 0, 0);
}

// ---------------- prep: rmsnorm (blocks 0..NROWS) + weight cvt (rest), 1 launch ----------------
#define CVT_N1 4194304   // in_proj
#define CVT_N2 196608    // x_proj
#define CVT_N3 131072    // dt_proj
#define CVT_N4 2097152   // out_proj
#define CVT_TOTAL (CVT_N1 + CVT_N2 + CVT_N3 + CVT_N4)   // 6,619,136 (/256 = 25856 blocks)
__global__ __launch_bounds__(256) void prep_kernel(const float* __restrict__ x, bf16* __restrict__ u,
                                                   const float* __restrict__ i1, bf16* __restrict__ o1,
                                                   const float* __restrict__ i2, bf16* __restrict__ o2,
                                                   const float* __restrict__ i3, bf16* __restrict__ o3,
                                                   const float* __restrict__ i4, bf16* __restrict__ o4) {
    if (blockIdx.x < NROWS) {
        const int r = blockIdx.x;
        const int t = threadIdx.x;
        const float4 v = reinterpret_cast<const float4*>(x + (size_t)r * DMODEL)[t];
        float ss = v.x * v.x + v.y * v.y + v.z * v.z + v.w * v.w;
        #pragma unroll
        for (int o = 32; o > 0; o >>= 1) ss += __shfl_down(ss, o);
        __shared__ float red[4];
        if ((t & 63) == 0) red[t >> 6] = ss;
        __syncthreads();
        const float tot = red[0] + red[1] + red[2] + red[3];
        const float rs = rsqrtf(tot * (1.0f / DMODEL) + 1e-6f);
        union { uint2 u2; bf16 h[4]; } o4v;
        o4v.h[0] = f2b(v.x * rs); o4v.h[1] = f2b(v.y * rs);
        o4v.h[2] = f2b(v.z * rs); o4v.h[3] = f2b(v.w * rs);
        *reinterpret_cast<uint2*>(u + (size_t)r * DMODEL + t * 4) = o4v.u2;
    } else {
        int i = (blockIdx.x - NROWS) * 256 + threadIdx.x;
        if (i < CVT_N1) { o1[i] = f2b(i1[i]); }
        i -= CVT_N1;
        if (i >= 0 && i < CVT_N2) { o2[i] = f2b(i2[i]); }
        i -= CVT_N2;
        if (i >= 0 && i < CVT_N3) { o3[i] = f2b(i3[i]); }
        i -= CVT_N3;
        if (i >= 0 && i < CVT_N4) { o4[i] = f2b(i4[i]); }
    }
}

// ---------------- causal depthwise conv (width 4) + silu, 4 channels/thread ----------------
__global__ __launch_bounds__(256) void conv_silu4_kernel(const bf16* __restrict__ xcraw,
                                                         const float* __restrict__ cw,
                                                         const float* __restrict__ cb,
                                                         bf16* __restrict__ xc) {
    const int t = blockIdx.x * 256 + threadIdx.x;          // over NROWS*DINNER/4
    const int e = (t << 2) & (DINNER - 1);                 // 4-aligned channel
    const int r = t >> 9;
    const int l = r & (SEQ_N - 1);
    float4 w0 = *reinterpret_cast<const float4*>(cw + (e + 0) * 4);
    float4 w1 = *reinterpret_cast<const float4*>(cw + (e + 1) * 4);
    float4 w2 = *reinterpret_cast<const float4*>(cw + (e + 2) * 4);
    float4 w3 = *reinterpret_cast<const float4*>(cw + (e + 3) * 4);
    const float4 bias = *reinterpret_cast<const float4*>(cb + e);
    float xs[4][4];   // [k][j]
    #pragma unroll
    for (int k = 0; k < 4; ++k) {
        const int lp = l - 3 + k;
        if (lp >= 0) {
            union { uint2 u; bf16 h[4]; } tmp;
            tmp.u = *reinterpret_cast<const uint2*>(xcraw + (size_t)(r - 3 + k) * DINNER + e);
            #pragma unroll
            for (int j = 0; j < 4; ++j) xs[k][j] = b2f(tmp.h[j]);
        } else {
            #pragma unroll
            for (int j = 0; j < 4; ++j) xs[k][j] = 0.f;
        }
    }
    float acc[4];
    acc[0] = bias.x + w0.x * xs[0][0] + w0.y * xs[1][0] + w0.z * xs[2][0] + w0.w * xs[3][0];
    acc[1] = bias.y + w1.x * xs[0][1] + w1.y * xs[1][1] + w1.z * xs[2][1] + w1.w * xs[3][1];
    acc[2] = bias.z + w2.x * xs[0][2] + w2.y * xs[1][2] + w2.z * xs[2][2] + w2.w * xs[3][2];
    acc[3] = bias.w + w3.x * xs[0][3] + w3.y * xs[1][3] + w3.z * xs[2][3] + w3.w * xs[3][3];
    union { uint2 u; bf16 h[4]; } o;
    #pragma unroll
    for (int j = 0; j < 4; ++j) o.h[j] = f2b(acc[j] / (1.f + __expf(-acc[j])));
    *reinterpret_cast<uint2*>(xc + (size_t)r * DINNER + e) = o.u;
}

// ============ MFMA bf16 GEMM (128x128 tile, syncthreads dbuf): C[M,N] = A[M,K] @ B[N,K]^T ============
// kept for the small GEMMs (x_proj N=128, dt_proj K=64).
// EPI 1: bf16 store, softplus(acc + aux[n])  (ldc=N).
// EPI 5: split-K partial: f32 store to Cout + blockIdx.z*NROWS*N, A/B advanced by z*K.
template <int EPI>
__global__ __launch_bounds__(256) void mfma_gemm(const bf16* __restrict__ A, int lda,
                                                 const bf16* __restrict__ B, int ldb,
                                                 void* __restrict__ Cout,
                                                 void* __restrict__ Cout2,
                                                 const float* __restrict__ aux,
                                                 int N, int K) {
    __shared__ __align__(16) bf16 sA[2][128 * 32];
    __shared__ __align__(16) bf16 sB[2][128 * 32];
    const int tid = threadIdx.x;
    const int w = tid >> 6;
    const int lane = tid & 63;
    const int quad = lane >> 4;
    const int l15 = lane & 15;
    const int m0 = blockIdx.x * 128;
    const int n0 = blockIdx.y * 128;
    const int wm = (w >> 1) * 64;
    const int wn = (w & 1) * 64;

    if constexpr (EPI == 5) {   // split-K: this block handles K-half blockIdx.z
        const int koff = blockIdx.z * K;
        A += koff;
        B += koff;
    }

    f32x4 acc[4][4];
    #pragma unroll
    for (int i = 0; i < 4; ++i)
        #pragma unroll
        for (int j = 0; j < 4; ++j)
            acc[i][j] = (f32x4){0.f, 0.f, 0.f, 0.f};

    const int sm = tid >> 2;
    const int q = (tid & 3) ^ ((sm >> 1) & 3);
    const bf16* gA0 = A + (size_t)(m0 + sm) * lda + q * 8;
    const bf16* gA1 = gA0 + (size_t)64 * lda;
    const bf16* gB0 = B + (size_t)(n0 + sm) * ldb + q * 8;
    const bf16* gB1 = gB0 + (size_t)64 * ldb;
    bf16* lA0c0 = sA[0] + w * 512;
    bf16* lA1c0 = sA[0] + 2048 + w * 512;
    bf16* lA0c1 = sA[1] + w * 512;
    bf16* lA1c1 = sA[1] + 2048 + w * 512;
    bf16* lB0c0 = sB[0] + w * 512;
    bf16* lB1c0 = sB[0] + 2048 + w * 512;
    bf16* lB0c1 = sB[1] + w * 512;
    bf16* lB1c1 = sB[1] + 2048 + w * 512;

    const int sw2 = (l15 >> 1) & 3;
    const int qx = (quad ^ sw2) * 8;

    for (int k0 = 0; k0 < K; k0 += 64) {
        gll16(gA0 + k0, lA0c0);
        gll16(gA1 + k0, lA1c0);
        gll16(gB0 + k0, lB0c0);
        gll16(gB1 + k0, lB1c0);
        gll16(gA0 + k0 + 32, lA0c1);
        gll16(gA1 + k0 + 32, lA1c1);
        gll16(gB0 + k0 + 32, lB0c1);
        gll16(gB1 + k0 + 32, lB1c1);
        __syncthreads();
        #pragma unroll
        for (int ch = 0; ch < 2; ++ch) {
            short8 af[4], bfr[4];
            #pragma unroll
            for (int f = 0; f < 4; ++f) {
                af[f]  = *reinterpret_cast<const short8*>(sA[ch] + (wm + f * 16 + l15) * 32 + qx);
                bfr[f] = *reinterpret_cast<const short8*>(sB[ch] + (wn + f * 16 + l15) * 32 + qx);
            }
            #pragma unroll
            for (int i = 0; i < 4; ++i)
                #pragma unroll
                for (int j = 0; j < 4; ++j)
                    acc[i][j] = __builtin_amdgcn_mfma_f32_16x16x32_bf16(af[i], bfr[j], acc[i][j], 0, 0, 0);
        }
        __syncthreads();
    }

    // epilogue: C/D layout col = lane&15, row = quad*4 + reg  [verified m89/m91]
    const int rbase = m0 + wm + quad * 4;
    if constexpr (EPI == 1) {
        bf16* C = (bf16*)Cout;
        #pragma unroll
        for (int i = 0; i < 4; ++i)
            #pragma unroll
            for (int r = 0; r < 4; ++r) {
                const size_t ro = (size_t)(rbase + i * 16 + r) * N;
                #pragma unroll
                for (int j = 0; j < 4; ++j) {
                    const int c = n0 + wn + j * 16 + l15;
                    float v = acc[i][j][r] + aux[c];
                    if (v < 15.f) v = __logf(1.f + __expf(v));   // softplus (fast, err ~1e-6)
                    C[ro + c] = f2b(v);
                }
            }
    } else {  // EPI == 5: f32 partial store (split-K)
        float* C = (float*)Cout + (size_t)blockIdx.z * NROWS * N;
        #pragma unroll
        for (int i = 0; i < 4; ++i)
            #pragma unroll
            for (int r = 0; r < 4; ++r) {
                const size_t ro = (size_t)(rbase + i * 16 + r) * N;
                #pragma unroll
                for (int j = 0; j < 4; ++j)
                    C[ro + n0 + wn + j * 16 + l15] = acc[i][j][r];
            }
    }
    (void)Cout2;
}

// ============ MFMA bf16 GEMM 256x256, counted-vmcnt 4-ring pipeline (out_proj) ============
// 512 threads = 8 waves (2 x 4); each wave owns a 128x64 C-tile (acc[8][4] f32x4).
// BK=32 per step; LDS ring of 4 slots x (A 256x32 | B 256x32) bf16 = 128 KiB.
// Schedule: per step t: s_waitcnt vmcnt(8) -> s_barrier -> ds_read 12 frags (slot t&3)
// -> STAGE(t+3) -> 32 MFMA. One barrier per step; vmcnt never 0 until the tail.
// Map: chunked XCD map (r0/r1-measured best for out_proj N=1024 K=2048: 32m x 1n
// strip/XCD, B fully L2-reused; 4x4-group ws at K=2048 is 8 MB > L2, cost ~18 us in r4).
// EPI 2: f32 store Cout = acc + aux[m*N+n] (residual).
template <int EPI>
__global__ __launch_bounds__(512, 2) void mfma_gemm256(const bf16* __restrict__ A, int lda,
                                                       const bf16* __restrict__ B, int ldb,
                                                       void* __restrict__ Cout,
                                                       void* __restrict__ Cout2,
                                                       const float* __restrict__ aux,
                                                       int N, int K) {
    __shared__ __align__(16) bf16 lds[4 * 16384];   // 128 KiB
    const int tid = threadIdx.x;
    const int w = tid >> 6;
    const int lane = tid & 63;
    const int quad = lane >> 4;
    const int l15 = lane & 15;
    // chunked XCD map: XCD gets a contiguous wg range; m varies fast, n slow
    const int nwg = gridDim.x;
    const int wg = (blockIdx.x & 7) * (nwg >> 3) + (blockIdx.x >> 3);
    const int m0 = (wg & 63) * 256;        // M = NROWS = 16384 -> 64 m-blocks (fixed)
    const int n0 = (wg >> 6) * 256;
    const int wr = w >> 2;                 // 0..1
    const int wc = w & 3;                  // 0..3

    f32x4 acc[8][4];
    #pragma unroll
    for (int i = 0; i < 8; ++i)
        #pragma unroll
        for (int j = 0; j < 4; ++j) acc[i][j] = (f32x4){0.f, 0.f, 0.f, 0.f};

    // staging: thread tid covers row (c*128 + tid>>2), 16B unit (tid&3), pre-swizzled source
    const int srow = tid >> 2;
    const int su = ((tid & 3) ^ ((tid >> 3) & 3)) * 8;   // element offset within BK
    const bf16* gA0 = A + (size_t)(m0 + srow) * lda + su;
    const bf16* gA1 = gA0 + (size_t)128 * lda;
    const bf16* gB0 = B + (size_t)(n0 + srow) * ldb + su;
    const bf16* gB1 = gB0 + (size_t)128 * ldb;
    const int wofs = w * 512;              // wave-uniform LDS stage base (elems)

    const int qx = (quad ^ ((l15 >> 1) & 3)) * 8;        // swizzled read unit (elems)
    const int arow = wr * 128 + l15;
    const int brow = wc * 64 + l15;
    const int nk = K >> 5;

    auto STAGE = [&](int s) {
        bf16* base = lds + (s & 3) * 16384;
        const size_t ko = (size_t)s * 32;
        gll16(gA0 + ko, base + wofs);
        gll16(gA1 + ko, base + 4096 + wofs);
        gll16(gB0 + ko, base + 8192 + wofs);
        gll16(gB1 + ko, base + 12288 + wofs);
    };
    STAGE(0); STAGE(1); STAGE(2);          // 12 loads in flight

    for (int t = 0; t < nk; ++t) {
        const int rem = nk - 1 - t;
        if (rem >= 2)      asm volatile("s_waitcnt vmcnt(8)" ::: "memory");
        else if (rem == 1) asm volatile("s_waitcnt vmcnt(4)" ::: "memory");
        else               asm volatile("s_waitcnt vmcnt(0)" ::: "memory");
        __builtin_amdgcn_s_barrier();
        asm volatile("" ::: "memory");     // keep LDS reads below the barrier
        const bf16* bufA = lds + (t & 3) * 16384;
        const bf16* bufB = bufA + 8192;
        short8 af[8], bfr[4];
        #pragma unroll
        for (int i = 0; i < 8; ++i)
            af[i] = *reinterpret_cast<const short8*>(bufA + (arow + i * 16) * 32 + qx);
        #pragma unroll
        for (int j = 0; j < 4; ++j)
            bfr[j] = *reinterpret_cast<const short8*>(bufB + (brow + j * 16) * 32 + qx);
        if (t + 3 < nk) STAGE(t + 3);      // into slot (t+3)&3 == (t-1)&3, freed by this barrier
        #pragma unroll
        for (int i = 0; i < 8; ++i)
            #pragma unroll
            for (int j = 0; j < 4; ++j)
                acc[i][j] = __builtin_amdgcn_mfma_f32_16x16x32_bf16(af[i], bfr[j], acc[i][j], 0, 0, 0);
    }

    // epilogue: C/D layout col = lane&15, row = quad*4 + reg  [verified m89/m91]
    const int rbase = m0 + wr * 128 + quad * 4;
    if constexpr (EPI == 2) {
        float* C = (float*)Cout;
        #pragma unroll
        for (int i = 0; i < 8; ++i)
            #pragma unroll
            for (int r = 0; r < 4; ++r) {
                const size_t ro = (size_t)(rbase + i * 16 + r) * N;
                #pragma unroll
                for (int j = 0; j < 4; ++j) {
                    const int c2 = n0 + wc * 64 + j * 16 + l15;
                    C[ro + c2] = acc[i][j][r] + aux[ro + c2];
                }
            }
    } else {  // EPI == 3: split bf16 store, cols [0,2048)->Cout else Cout2, both ldc=2048
        bf16* C = (bf16*)((n0 < 2048) ? Cout : Cout2);
        const int cb = (n0 & 2047) + wc * 64;
        #pragma unroll
        for (int i = 0; i < 8; ++i)
            #pragma unroll
            for (int r = 0; r < 4; ++r) {
                const size_t ro = (size_t)(rbase + i * 16 + r) * 2048;
                #pragma unroll
                for (int j = 0; j < 4; ++j)
                    C[ro + cb + j * 16 + l15] = f2b(acc[i][j][r]);
            }
    }
    (void)aux;
}

// ============ MFMA bf16 GEMM 256x128, ring-3 counted-vmcnt, 2 blocks/CU (in_proj) ============
// 256 threads = 4 waves (2M x 2N); per-wave body IDENTICAL to mfma_gemm256 (wave tile
// 128x64, acc[8][4], 12 ds_read + 32 MFMA per BK=32 step). LDS ring of 3 slots x
// (A 256x32 | B 128x32) = 3 x 24 KB = 72 KiB -> 2 blocks/CU (144 KiB): two independently
// synchronized blocks per CU so one computes while the other sits in barrier/vmcnt
// (r4/r7 diagnosis: 1-block/CU lockstep was latency-bound at 43% MfmaUtil, 21% HBM).
// STAGE = 6 gll16/thread (A rows +0/64/128/192, B rows +0/64); prefetch distance 2;
// per step: vmcnt(6) [slot t drained, slot t+1's 6 in flight] -> s_barrier -> ds_read
// (slot t%3) -> STAGE(t+2) [slot (t+2)%3 == (t-1)%3, freed by this barrier] -> 32 MFMA.
// Map: XCD owns 8m x 32n, traversed in 4x4 tile groups (group ws = 4x512K A + 4x256K B
// = 3 MB < 4 MB L2). XOR swizzle identical to mfma_gemm256 (conflict-free, measured 0).
// EPI 3 only: split bf16 store, cols [0,2048)->Cout else Cout2, both ldc=2048.
__global__ __launch_bounds__(256, 2) void mfma_gemm256x128(const bf16* __restrict__ A, int lda,
                                                           const bf16* __restrict__ B, int ldb,
                                                           void* __restrict__ Cout,
                                                           void* __restrict__ Cout2,
                                                           int K) {
    __shared__ __align__(16) bf16 lds[3 * 12288];   // 72 KiB
    const int tid = threadIdx.x;
    const int w = tid >> 6;                // 0..3
    const int lane = tid & 63;
    const int quad = lane >> 4;
    const int l15 = lane & 15;
    // L2-blocked map: XCD owns 8m x 32n in 4x4 groups (bijective: nwg = 2048)
    const int xcd = blockIdx.x & 7;
    const int c = blockIdx.x >> 3;         // [0, 256)
    const int g = c >> 4;                  // [0, 16)
    const int gm = g >> 3;                 // [0, 2)
    const int gn = g & 7;                  // [0, 8)
    const int m0 = (xcd * 8 + gm * 4 + ((c >> 2) & 3)) * 256;
    const int n0 = (gn * 4 + (c & 3)) * 128;
    const int wr = w >> 1;                 // 0..1 (m)
    const int wn_ = w & 1;                 // 0..1 (n)

    f32x4 acc[8][4];
    #pragma unroll
    for (int i = 0; i < 8; ++i)
        #pragma unroll
        for (int j = 0; j < 4; ++j) acc[i][j] = (f32x4){0.f, 0.f, 0.f, 0.f};

    // staging: per 4KB round, thread covers row (tid>>2) + round*64, 16B unit (tid&3),
    // pre-swizzled source (round offset 64 preserves (row>>1)&3).
    const int srow = tid >> 2;             // [0, 64)
    const int su = ((tid & 3) ^ ((srow >> 1) & 3)) * 8;
    const bf16* gA = A + (size_t)(m0 + srow) * lda + su;
    const bf16* gB = B + (size_t)(n0 + srow) * ldb + su;
    const int wofs = w * 512;              // wave-uniform dest base within a round (elems)

    const int qx = (quad ^ ((l15 >> 1) & 3)) * 8;        // swizzled read unit (elems)
    const int arow = wr * 128 + l15;
    const int brow = wn_ * 64 + l15;
    const int nk = K >> 5;                 // BK=32 steps (nk = 32 for in_proj)

    auto STAGE = [&](int s) {
        bf16* base = lds + (s % 3) * 12288;
        const size_t ko = (size_t)s * 32;
        gll16(gA + ko,                          base + wofs);            // A rows   0- 63
        gll16(gA + (size_t)64 * lda + ko,       base + 2048 + wofs);     // A rows  64-127
        gll16(gA + (size_t)128 * lda + ko,      base + 4096 + wofs);     // A rows 128-191
        gll16(gA + (size_t)192 * lda + ko,      base + 6144 + wofs);     // A rows 192-255
        gll16(gB + ko,                          base + 8192 + wofs);     // B rows   0- 63
        gll16(gB + (size_t)64 * ldb + ko,       base + 10240 + wofs);    // B rows  64-127
    };
    STAGE(0); STAGE(1);                    // 12 loads in flight

    for (int t = 0; t < nk; ++t) {
        if (t + 1 < nk) asm volatile("s_waitcnt vmcnt(6)" ::: "memory");
        else            asm volatile("s_waitcnt vmcnt(0)" ::: "memory");
        __builtin_amdgcn_s_barrier();
        asm volatile("" ::: "memory");     // keep LDS reads below the barrier
        const bf16* bufA = lds + (t % 3) * 12288;
        const bf16* bufB = bufA + 8192;
        short8 af[8], bfr[4];
        #pragma unroll
        for (int i = 0; i < 8; ++i)
            af[i] = *reinterpret_cast<const short8*>(bufA + (arow + i * 16) * 32 + qx);
        #pragma unroll
        for (int j = 0; j < 4; ++j)
            bfr[j] = *reinterpret_cast<const short8*>(bufB + (brow + j * 16) * 32 + qx);
        if (t + 2 < nk) STAGE(t + 2);      // slot (t+2)%3 == (t-1)%3, freed by this barrier
        #pragma unroll
        for (int i = 0; i < 8; ++i)
            #pragma unroll
            for (int j = 0; j < 4; ++j)
                acc[i][j] = __builtin_amdgcn_mfma_f32_16x16x32_bf16(af[i], bfr[j], acc[i][j], 0, 0, 0);
    }

    // epilogue: split bf16 store (EPI 3), C/D layout col = lane&15, row = quad*4 + reg
    const int rbase = m0 + wr * 128 + quad * 4;
    bf16* C = (bf16*)((n0 < 2048) ? Cout : Cout2);
    const int cb = (n0 & 2047) + wn_ * 64;
    #pragma unroll
    for (int i = 0; i < 8; ++i)
        #pragma unroll
        for (int r = 0; r < 4; ++r) {
            const size_t ro = (size_t)(rbase + i * 16 + r) * 2048;
            #pragma unroll
            for (int j = 0; j < 4; ++j)
                C[ro + cb + j * 16 + l15] = f2b(acc[i][j][r]);
        }
}

// ---------------- x_proj split-K combine: p0+p1 -> dtr (bf16) + bcbuf (f32) ----------------
__global__ __launch_bounds__(256) void combine_xproj(const float* __restrict__ p0,
                                                     const float* __restrict__ p1,
                                                     bf16* __restrict__ dtr,
                                                     float* __restrict__ bcbuf) {
    const int idx = blockIdx.x * 256 + threadIdx.x;   // over NROWS*128
    const int c = idx & 127;
    const int row = idx >> 7;
    const float v = p0[idx] + p1[idx];
    if (c < 64) dtr[(size_t)row * 64 + c] = f2b(v);
    else if (c < 96) bcbuf[(size_t)row * 32 + (c - 64)] = v;
}

// ============== chunked selective scan (3 passes), NC = chunk count ==============
__device__ __forceinline__ bool pow_ok(const float* a) {
    bool ok = true;
    #pragma unroll
    for (int s = 1; s < 16; ++s) {
        const float t = a[0] * (s + 1);
        ok = ok && (fabsf(a[s] - t) <= 1e-4f * fabsf(t) + 1e-6f);
    }
    return ok;
}

template <int NC>
__global__ __launch_bounds__(256) void scan_passA(const bf16* __restrict__ dt,
                                                  const bf16* __restrict__ xc,
                                                  const float* __restrict__ bcbuf,
                                                  const float* __restrict__ A_log,
                                                  float* __restrict__ hend,
                                                  float* __restrict__ sumdt) {
    constexpr int LC = SEQ_N / NC;
    __shared__ __align__(16) float sbc[LC * 32];
    const int e = blockIdx.x * 256 + threadIdx.x;
    const int c = blockIdx.y;
    const int b = blockIdx.z;
    const size_t rbase = (size_t)b * SEQ_N + (size_t)c * LC;
    #pragma unroll
    for (int idx = threadIdx.x; idx < LC * 8; idx += 256)
        reinterpret_cast<float4*>(sbc)[idx] =
            reinterpret_cast<const float4*>(bcbuf + rbase * 32)[idx];
    float a[16], h[16];
    #pragma unroll
    for (int s = 0; s < 16; ++s) {
        a[s] = -__expf(A_log[e * 16 + s]);
        h[s] = 0.f;
    }
    const bool pw = pow_ok(a);
    float sd = 0.f;
    __syncthreads();
    for (int i = 0; i < LC; ++i) {
        const size_t row = rbase + i;
        const float dtv = b2f(dt[row * DINNER + e]);
        const float xv = b2f(xc[row * DINNER + e]);
        const float cdx = dtv * xv;
        const float4* bp = reinterpret_cast<const float4*>(sbc + i * 32);
        float Bv[16];
        *reinterpret_cast<float4*>(&Bv[0])  = bp[0];
        *reinterpret_cast<float4*>(&Bv[4])  = bp[1];
        *reinterpret_cast<float4*>(&Bv[8])  = bp[2];
        *reinterpret_cast<float4*>(&Bv[12]) = bp[3];
        sd += dtv;
        if (pw) {
            const float e1 = __expf(dtv * a[0]);
            float dAp = 1.f;
            #pragma unroll
            for (int s = 0; s < 16; ++s) {
                dAp *= e1;
                h[s] = fmaf(h[s], dAp, cdx * Bv[s]);
            }
        } else {
            #pragma unroll
            for (int s = 0; s < 16; ++s) {
                const float dA = __expf(dtv * a[s]);
                h[s] = fmaf(h[s], dA, cdx * Bv[s]);
            }
        }
    }
    const size_t o = ((size_t)b * NC + c) * DINNER + e;
    #pragma unroll
    for (int s = 0; s < 16; s += 4) {
        float4 v = {h[s], h[s + 1], h[s + 2], h[s + 3]};
        *reinterpret_cast<float4*>(hend + o * 16 + s) = v;
    }
    sumdt[o] = sd;
}

template <int NC>
__global__ __launch_bounds__(256) void scan_passB(float* hstate,
                                                  const float* __restrict__ sumdt,
                                                  const float* __restrict__ A_log) {
    const int g = blockIdx.x * 256 + threadIdx.x;
    const int s = g & 15;
    const int e = (g >> 4) & (DINNER - 1);
    const int b = g >> 15;
    const float a = -__expf(A_log[e * 16 + s]);
    float H = 0.f;
    for (int c = 0; c < NC; ++c) {
        const size_t o = ((size_t)b * NC + c) * DINNER + e;
        const float he = hstate[o * 16 + s];
        const float sd = sumdt[o];
        hstate[o * 16 + s] = H;
        H = fmaf(H, __expf(a * sd), he);
    }
}

template <int NC>
__global__ __launch_bounds__(256) void scan_passC(const bf16* dt,
                                                  const bf16* __restrict__ xc,
                                                  const bf16* __restrict__ z,
                                                  const float* __restrict__ bcbuf,
                                                  const float* __restrict__ A_log,
                                                  const float* __restrict__ D_skip,
                                                  const float* __restrict__ hinit,
                                                  bf16* y) {
    constexpr int LC = SEQ_N / NC;
    __shared__ __align__(16) float sbc[LC * 32];
    const int e = blockIdx.x * 256 + threadIdx.x;
    const int c = blockIdx.y;
    const int b = blockIdx.z;
    const size_t rbase = (size_t)b * SEQ_N + (size_t)c * LC;
    #pragma unroll
    for (int idx = threadIdx.x; idx < LC * 8; idx += 256)
        reinterpret_cast<float4*>(sbc)[idx] =
            reinterpret_cast<const float4*>(bcbuf + rbase * 32)[idx];
    float a[16], h[16];
    #pragma unroll
    for (int s = 0; s < 16; ++s) a[s] = -__expf(A_log[e * 16 + s]);
    const bool pw = pow_ok(a);
    const float dsk = D_skip[e];
    const size_t o = ((size_t)b * NC + c) * DINNER + e;
    #pragma unroll
    for (int s = 0; s < 16; s += 4) {
        float4 v = *reinterpret_cast<const float4*>(hinit + o * 16 + s);
        h[s] = v.x; h[s + 1] = v.y; h[s + 2] = v.z; h[s + 3] = v.w;
    }
    __syncthreads();
    for (int i = 0; i < LC; ++i) {
        const size_t row = rbase + i;
        const float dtv = b2f(dt[row * DINNER + e]);
        const float xv = b2f(xc[row * DINNER + e]);
        const float zv = b2f(z[row * DINNER + e]);
        const float cdx = dtv * xv;
        const float4* bp = reinterpret_cast<const float4*>(sbc + i * 32);
        float Bv[16], Cv[16];
        *reinterpret_cast<float4*>(&Bv[0])  = bp[0];
        *reinterpret_cast<float4*>(&Bv[4])  = bp[1];
        *reinterpret_cast<float4*>(&Bv[8])  = bp[2];
        *reinterpret_cast<float4*>(&Bv[12]) = bp[3];
        *reinterpret_cast<float4*>(&Cv[0])  = bp[4];
        *reinterpret_cast<float4*>(&Cv[4])  = bp[5];
        *reinterpret_cast<float4*>(&Cv[8])  = bp[6];
        *reinterpret_cast<float4*>(&Cv[12]) = bp[7];
        float yv = 0.f;
        if (pw) {
            const float e1 = __expf(dtv * a[0]);
            float dAp = 1.f;
            #pragma unroll
            for (int s = 0; s < 16; ++s) {
                dAp *= e1;
                h[s] = fmaf(h[s], dAp, cdx * Bv[s]);
                yv = fmaf(h[s], Cv[s], yv);
            }
        } else {
            #pragma unroll
            for (int s = 0; s < 16; ++s) {
                const float dA = __expf(dtv * a[s]);
                h[s] = fmaf(h[s], dA, cdx * Bv[s]);
                yv = fmaf(h[s], Cv[s], yv);
            }
        }
        const float g = (yv + dsk * xv) * (zv / (1.f + __expf(-zv)));
        y[row * DINNER + e] = f2b(g);
    }
}

extern "C" void kernel_launch(void* const* d_in, const int* in_sizes, int n_in,
                              void* d_out, int out_size, void* d_ws, size_t ws_size,
                              hipStream_t stream) {
    const float* x         = (const float*)d_in[0];
    const float* in_proj_w = (const float*)d_in[1];
    const float* conv_w    = (const float*)d_in[2];
    const float* conv_b    = (const float*)d_in[3];
    const float* x_proj_w  = (const float*)d_in[4];
    const float* dt_proj_w = (const float*)d_in[5];
    const float* dt_proj_b = (const float*)d_in[6];
    const float* A_log     = (const float*)d_in[7];
    const float* D_skip    = (const float*)d_in[8];
    const float* out_proj_w= (const float*)d_in[9];
    float* out = (float*)d_out;

    // workspace layout (bytes)
    char* ws = (char*)d_ws;
    bf16*  xcraw = (bf16*)(ws + 0);            // 67,108,864  [-> dtb -> y]
    bf16*  xc    = (bf16*)(ws + 67108864);     // 67,108,864  [u lives here first]
    bf16*  dtr   = (bf16*)(ws + 134217728);    //  2,097,152  [16384 x 64 bf16]
    float* bcbuf = (float*)(ws + 136314880);   //  2,097,152  [16384 x 32 f32]
    bf16*  w_in  = (bf16*)(ws + 140509184);    //  8,388,608
    bf16*  w_xp  = (bf16*)(ws + 148897792);    //    524,288  [padded to 128 x 2048]
    bf16*  w_dt  = (bf16*)(ws + 149422080);    //    262,144
    bf16*  w_out = (bf16*)(ws + 149684224);    //  4,194,304
    float* hend  = (float*)(ws + 153878528);   // NC=64: 33,554,432 | NC=32: 16,777,216
    bf16*  u     = xc;
    bf16*  dtb   = xcraw;
    bf16*  yb    = dtb;
    bf16*  zbuf  = (bf16*)d_out;               // z in d_out; overwritten by out-proj last
    // x_proj split-K partials alias hend (dead until scanA): 2 x 8 MB f32
    float* xp_p0 = hend;
    float* xp_p1 = hend + (size_t)NROWS * 128;

    const bool big = (ws_size >= 189530112ULL);   // room for NC=64 layout?
    float* sumdt = (float*)(ws + (big ? 187432960 : 170655744));

    // 0+1. weight converts + rmsnorm (single launch)
    prep_kernel<<<NROWS + CVT_TOTAL / 256, 256, 0, stream>>>(
        x, u, in_proj_w, w_in, x_proj_w, w_xp, dt_proj_w, w_dt, out_proj_w, w_out);
    // 2. xz = u @ in_proj^T, split-stored: cols [0,2048)->xcraw, [2048,4096)->zbuf
    //    256x128 tile, ring-3 (72 KiB), 2 blocks/CU — occupancy experiment (r7 diagnosis)
    mfma_gemm256x128<<<dim3((NROWS / 256) * (4096 / 128)), 256, 0, stream>>>(
        u, DMODEL, w_in, DMODEL, xcraw, zbuf, DMODEL);
    // 3. conv + silu -> xc (overwrites u; reads only xcraw)
    conv_silu4_kernel<<<(NROWS * DINNER) / 1024, 256, 0, stream>>>(xcraw, conv_w, conv_b, xc);
    // 4. x_proj split-K=2: partials (f32, N=128) -> combine into dtr + bcbuf
    mfma_gemm<5><<<dim3(NROWS / 128, 1, 2), 256, 0, stream>>>(
        xc, DINNER, w_xp, DINNER, xp_p0, nullptr, nullptr, 128, DINNER / 2);
    combine_xproj<<<(NROWS * 128) / 256, 256, 0, stream>>>(xp_p0, xp_p1, dtr, bcbuf);
    // 5. dt = softplus(dtr @ dt_proj^T + b)  [16384, 2048]  (over xcraw)
    mfma_gemm<1><<<dim3(NROWS / 128, DINNER / 128), 256, 0, stream>>>(
        dtr, DTRANK, w_dt, DTRANK, dtb, nullptr, dt_proj_b, DINNER, DTRANK);
    // 6. chunked selective scan, NC=64 (r1/r6 A-B: NC=32 halves scan occupancy, +13 us total)
    if (big) {
        scan_passA<64><<<dim3(DINNER / 256, 64, BATCH_N), 256, 0, stream>>>(
            dtb, xc, bcbuf, A_log, hend, sumdt);
        scan_passB<64><<<(BATCH_N * DINNER * DSTATE) / 256, 256, 0, stream>>>(hend, sumdt, A_log);
        scan_passC<64><<<dim3(DINNER / 256, 64, BATCH_N), 256, 0, stream>>>(
            dtb, xc, zbuf, bcbuf, A_log, D_skip, hend, yb);
    } else {
        scan_passA<32><<<dim3(DINNER / 256, 32, BATCH_N), 256, 0, stream>>>(
            dtb, xc, bcbuf, A_log, hend, sumdt);
        scan_passB<32><<<(BATCH_N * DINNER * DSTATE) / 256, 256, 0, stream>>>(hend, sumdt, A_log);
        scan_passC<32><<<dim3(DINNER / 256, 32, BATCH_N), 256, 0, stream>>>(
            dtb, xc, zbuf, bcbuf, A_log, D_skip, hend, yb);
    }
    // 7. out = x + y @ out_proj^T  [16384, 1024]
    mfma_gemm256<2><<<dim3((NROWS / 256) * (DMODEL / 256)), 512, 0, stream>>>(
        yb, DINNER, w_out, DINNER, out, nullptr, x, DMODEL, DINNER);
    (void)in_sizes; (void)n_in; (void)out_size;
}

// Round 10
// 650.345 us; speedup vs baseline: 1.0305x; 1.0305x over previous
//
#include <hip/hip_runtime.h>
#include <hip/hip_bf16.h>
#include <math.h>

typedef __hip_bfloat16 bf16;
typedef __attribute__((ext_vector_type(8))) short short8;   // 8 bf16 (4 VGPRs) MFMA A/B frag
typedef __attribute__((ext_vector_type(4))) float f32x4;    // MFMA C/D frag

#define BATCH_N 4
#define SEQ_N 4096
#define DMODEL 1024
#define DINNER 2048
#define DTRANK 64
#define DSTATE 16
#define NROWS (BATCH_N * SEQ_N)   // 16384

__device__ __forceinline__ float b2f(bf16 v) { return __bfloat162float(v); }
__device__ __forceinline__ bf16 f2b(float v) { return __float2bfloat16(v); }

// async global->LDS, 16B per lane. ldsbase must be wave-uniform; HW adds lane*16.
__device__ __forceinline__ void gll16(const bf16* g, bf16* l) {
    __builtin_amdgcn_global_load_lds((const __attribute__((address_space(1))) unsigned int*)g,
                                     (__attribute__((address_space(3))) unsigned int*)l,
                                     16, 0, 0);
}

// ---------------- prep: rmsnorm (blocks 0..NROWS) + weight cvt x4 (rest), 1 launch ----------------
#define CVT_N1 4194304   // in_proj
#define CVT_N2 196608    // x_proj
#define CVT_N3 131072    // dt_proj
#define CVT_N4 2097152   // out_proj
#define CVT_TOTAL (CVT_N1 + CVT_N2 + CVT_N3 + CVT_N4)   // 6,619,136 (/1024 = 6464 blocks)
__device__ __forceinline__ void cvt4(bf16* dst, const float* src) {
    const float4 v = *reinterpret_cast<const float4*>(src);
    union { uint2 u2; bf16 h[4]; } t;
    t.h[0] = f2b(v.x); t.h[1] = f2b(v.y); t.h[2] = f2b(v.z); t.h[3] = f2b(v.w);
    *reinterpret_cast<uint2*>(dst) = t.u2;
}
__global__ __launch_bounds__(256) void prep_kernel(const float* __restrict__ x, bf16* __restrict__ u,
                                                   const float* __restrict__ i1, bf16* __restrict__ o1,
                                                   const float* __restrict__ i2, bf16* __restrict__ o2,
                                                   const float* __restrict__ i3, bf16* __restrict__ o3,
                                                   const float* __restrict__ i4, bf16* __restrict__ o4) {
    if (blockIdx.x < NROWS) {
        const int r = blockIdx.x;
        const int t = threadIdx.x;
        const float4 v = reinterpret_cast<const float4*>(x + (size_t)r * DMODEL)[t];
        float ss = v.x * v.x + v.y * v.y + v.z * v.z + v.w * v.w;
        #pragma unroll
        for (int o = 32; o > 0; o >>= 1) ss += __shfl_down(ss, o);
        __shared__ float red[4];
        if ((t & 63) == 0) red[t >> 6] = ss;
        __syncthreads();
        const float tot = red[0] + red[1] + red[2] + red[3];
        const float rs = rsqrtf(tot * (1.0f / DMODEL) + 1e-6f);
        union { uint2 u2; bf16 h[4]; } o4v;
        o4v.h[0] = f2b(v.x * rs); o4v.h[1] = f2b(v.y * rs);
        o4v.h[2] = f2b(v.z * rs); o4v.h[3] = f2b(v.w * rs);
        *reinterpret_cast<uint2*>(u + (size_t)r * DMODEL + t * 4) = o4v.u2;
    } else {
        // 4 elems/thread (all CVT_N* divisible by 4 -> a 4-chunk never straddles arrays)
        int i = (blockIdx.x - NROWS) * 1024 + threadIdx.x * 4;
        if (i < CVT_N1) { cvt4(o1 + i, i1 + i); }
        i -= CVT_N1;
        if (i >= 0 && i < CVT_N2) { cvt4(o2 + i, i2 + i); }
        i -= CVT_N2;
        if (i >= 0 && i < CVT_N3) { cvt4(o3 + i, i3 + i); }
        i -= CVT_N3;
        if (i >= 0 && i < CVT_N4) { cvt4(o4 + i, i4 + i); }
    }
}

// ---------------- causal depthwise conv (width 4) + silu, 4 channels/thread ----------------
__global__ __launch_bounds__(256) void conv_silu4_kernel(const bf16* __restrict__ xcraw,
                                                         const float* __restrict__ cw,
                                                         const float* __restrict__ cb,
                                                         bf16* __restrict__ xc) {
    const int t = blockIdx.x * 256 + threadIdx.x;          // over NROWS*DINNER/4
    const int e = (t << 2) & (DINNER - 1);                 // 4-aligned channel
    const int r = t >> 9;
    const int l = r & (SEQ_N - 1);
    float4 w0 = *reinterpret_cast<const float4*>(cw + (e + 0) * 4);
    float4 w1 = *reinterpret_cast<const float4*>(cw + (e + 1) * 4);
    float4 w2 = *reinterpret_cast<const float4*>(cw + (e + 2) * 4);
    float4 w3 = *reinterpret_cast<const float4*>(cw + (e + 3) * 4);
    const float4 bias = *reinterpret_cast<const float4*>(cb + e);
    float xs[4][4];   // [k][j]
    #pragma unroll
    for (int k = 0; k < 4; ++k) {
        const int lp = l - 3 + k;
        if (lp >= 0) {
            union { uint2 u; bf16 h[4]; } tmp;
            tmp.u = *reinterpret_cast<const uint2*>(xcraw + (size_t)(r - 3 + k) * DINNER + e);
            #pragma unroll
            for (int j = 0; j < 4; ++j) xs[k][j] = b2f(tmp.h[j]);
        } else {
            #pragma unroll
            for (int j = 0; j < 4; ++j) xs[k][j] = 0.f;
        }
    }
    float acc[4];
    acc[0] = bias.x + w0.x * xs[0][0] + w0.y * xs[1][0] + w0.z * xs[2][0] + w0.w * xs[3][0];
    acc[1] = bias.y + w1.x * xs[0][1] + w1.y * xs[1][1] + w1.z * xs[2][1] + w1.w * xs[3][1];
    acc[2] = bias.z + w2.x * xs[0][2] + w2.y * xs[1][2] + w2.z * xs[2][2] + w2.w * xs[3][2];
    acc[3] = bias.w + w3.x * xs[0][3] + w3.y * xs[1][3] + w3.z * xs[2][3] + w3.w * xs[3][3];
    union { uint2 u; bf16 h[4]; } o;
    #pragma unroll
    for (int j = 0; j < 4; ++j) o.h[j] = f2b(acc[j] / (1.f + __expf(-acc[j])));
    *reinterpret_cast<uint2*>(xc + (size_t)r * DINNER + e) = o.u;
}

// ============ MFMA bf16 GEMM (128x128 tile, syncthreads dbuf): C[M,N] = A[M,K] @ B[N,K]^T ============
// kept for the small GEMMs (x_proj N=128, dt_proj K=64).
// EPI 1: bf16 store, softplus(acc + aux[n])  (ldc=N).
// EPI 5: split-K partial: f32 store to Cout + blockIdx.z*NROWS*N, A/B advanced by z*K.
template <int EPI>
__global__ __launch_bounds__(256) void mfma_gemm(const bf16* __restrict__ A, int lda,
                                                 const bf16* __restrict__ B, int ldb,
                                                 void* __restrict__ Cout,
                                                 void* __restrict__ Cout2,
                                                 const float* __restrict__ aux,
                                                 int N, int K) {
    __shared__ __align__(16) bf16 sA[2][128 * 32];
    __shared__ __align__(16) bf16 sB[2][128 * 32];
    const int tid = threadIdx.x;
    const int w = tid >> 6;
    const int lane = tid & 63;
    const int quad = lane >> 4;
    const int l15 = lane & 15;
    const int m0 = blockIdx.x * 128;
    const int n0 = blockIdx.y * 128;
    const int wm = (w >> 1) * 64;
    const int wn = (w & 1) * 64;

    if constexpr (EPI == 5) {   // split-K: this block handles K-half blockIdx.z
        const int koff = blockIdx.z * K;
        A += koff;
        B += koff;
    }

    f32x4 acc[4][4];
    #pragma unroll
    for (int i = 0; i < 4; ++i)
        #pragma unroll
        for (int j = 0; j < 4; ++j)
            acc[i][j] = (f32x4){0.f, 0.f, 0.f, 0.f};

    const int sm = tid >> 2;
    const int q = (tid & 3) ^ ((sm >> 1) & 3);
    const bf16* gA0 = A + (size_t)(m0 + sm) * lda + q * 8;
    const bf16* gA1 = gA0 + (size_t)64 * lda;
    const bf16* gB0 = B + (size_t)(n0 + sm) * ldb + q * 8;
    const bf16* gB1 = gB0 + (size_t)64 * ldb;
    bf16* lA0c0 = sA[0] + w * 512;
    bf16* lA1c0 = sA[0] + 2048 + w * 512;
    bf16* lA0c1 = sA[1] + w * 512;
    bf16* lA1c1 = sA[1] + 2048 + w * 512;
    bf16* lB0c0 = sB[0] + w * 512;
    bf16* lB1c0 = sB[0] + 2048 + w * 512;
    bf16* lB0c1 = sB[1] + w * 512;
    bf16* lB1c1 = sB[1] + 2048 + w * 512;

    const int sw2 = (l15 >> 1) & 3;
    const int qx = (quad ^ sw2) * 8;

    for (int k0 = 0; k0 < K; k0 += 64) {
        gll16(gA0 + k0, lA0c0);
        gll16(gA1 + k0, lA1c0);
        gll16(gB0 + k0, lB0c0);
        gll16(gB1 + k0, lB1c0);
        gll16(gA0 + k0 + 32, lA0c1);
        gll16(gA1 + k0 + 32, lA1c1);
        gll16(gB0 + k0 + 32, lB0c1);
        gll16(gB1 + k0 + 32, lB1c1);
        __syncthreads();
        #pragma unroll
        for (int ch = 0; ch < 2; ++ch) {
            short8 af[4], bfr[4];
            #pragma unroll
            for (int f = 0; f < 4; ++f) {
                af[f]  = *reinterpret_cast<const short8*>(sA[ch] + (wm + f * 16 + l15) * 32 + qx);
                bfr[f] = *reinterpret_cast<const short8*>(sB[ch] + (wn + f * 16 + l15) * 32 + qx);
            }
            #pragma unroll
            for (int i = 0; i < 4; ++i)
                #pragma unroll
                for (int j = 0; j < 4; ++j)
                    acc[i][j] = __builtin_amdgcn_mfma_f32_16x16x32_bf16(af[i], bfr[j], acc[i][j], 0, 0, 0);
        }
        __syncthreads();
    }

    // epilogue: C/D layout col = lane&15, row = quad*4 + reg  [verified m89/m91]
    const int rbase = m0 + wm + quad * 4;
    if constexpr (EPI == 1) {
        bf16* C = (bf16*)Cout;
        #pragma unroll
        for (int i = 0; i < 4; ++i)
            #pragma unroll
            for (int r = 0; r < 4; ++r) {
                const size_t ro = (size_t)(rbase + i * 16 + r) * N;
                #pragma unroll
                for (int j = 0; j < 4; ++j) {
                    const int c = n0 + wn + j * 16 + l15;
                    float v = acc[i][j][r] + aux[c];
                    if (v < 15.f) v = __logf(1.f + __expf(v));   // softplus (fast, err ~1e-6)
                    C[ro + c] = f2b(v);
                }
            }
    } else {  // EPI == 5: f32 partial store (split-K)
        float* C = (float*)Cout + (size_t)blockIdx.z * NROWS * N;
        #pragma unroll
        for (int i = 0; i < 4; ++i)
            #pragma unroll
            for (int r = 0; r < 4; ++r) {
                const size_t ro = (size_t)(rbase + i * 16 + r) * N;
                #pragma unroll
                for (int j = 0; j < 4; ++j)
                    C[ro + n0 + wn + j * 16 + l15] = acc[i][j][r];
            }
    }
    (void)Cout2;
}

// ============ MFMA bf16 GEMM 256x256, counted-vmcnt 4-ring pipeline, per-shape XCD map ============
// 512 threads = 8 waves (2 x 4); each wave owns a 128x64 C-tile (acc[8][4] f32x4).
// BK=32 per step; LDS ring of 4 slots x (A 256x32 | B 256x32) bf16 = 128 KiB.
// Schedule (best-measured, r4/r6/r7): per step t: s_waitcnt vmcnt(8) [slot t resident;
// 8 loads stay in flight across the barrier] -> s_barrier -> ds_read 12 frags (slot
// t&3) -> STAGE(t+3) -> 32 MFMA. One barrier per step; vmcnt never 0 until the tail.
// Map (measured r1/r4/r6/r7): N==4096 (in_proj, K=1024) -> L2-blocked 4x4 groups per
// XCD (group ws = 4 MB = one XCD L2; FETCH 270->98 MB, dur 150->139-140). N==1024
// (out_proj, K=2048) -> chunked map (32m x 1n strip/XCD, B fully L2-reused; 4x4-group
// ws at K=2048 is 8 MB > L2, cost ~18 us in r4). r8 falsified the 256x128 2-block
// variant (same 8 waves/CU, lower intensity: 140->155 us) — this geometry is final.
// XOR swizzle (involution both sides): LDS[row][u] holds global unit u ^ ((row>>1)&3)
// (16B units); read at quad ^ ((l15>>1)&3) -> conflict-free (measured 0).
// EPI 2: f32 store Cout = acc + aux[m*N+n] (residual).  EPI 3: split bf16 store (ldc=2048).
template <int EPI>
__global__ __launch_bounds__(512, 2) void mfma_gemm256(const bf16* __restrict__ A, int lda,
                                                       const bf16* __restrict__ B, int ldb,
                                                       void* __restrict__ Cout,
                                                       void* __restrict__ Cout2,
                                                       const float* __restrict__ aux,
                                                       int N, int K) {
    __shared__ __align__(16) bf16 lds[4 * 16384];   // 128 KiB
    const int tid = threadIdx.x;
    const int w = tid >> 6;
    const int lane = tid & 63;
    const int quad = lane >> 4;
    const int l15 = lane & 15;
    int m0, n0;
    if (N == 4096) {
        // L2-blocked map: XCD owns 8m x 16n, traversed in 4x4 tile groups (bijective: nwg=1024)
        const int xcd = blockIdx.x & 7;
        const int c = blockIdx.x >> 3;         // [0, 128)
        const int g = c >> 4;                  // [0, 8)
        const int gm = g >> 2;                 // [0, 2)
        const int gn = g & 3;                  // [0, 4)
        m0 = (xcd * 8 + gm * 4 + ((c >> 2) & 3)) * 256;
        n0 = (gn * 4 + (c & 3)) * 256;
    } else {
        // chunked XCD map (r0): XCD gets a contiguous wg range; m varies, n slow
        const int nwg = gridDim.x;
        const int wg = (blockIdx.x & 7) * (nwg >> 3) + (blockIdx.x >> 3);
        m0 = (wg & 63) * 256;                  // M = NROWS = 16384 -> 64 m-blocks (fixed)
        n0 = (wg >> 6) * 256;
    }
    const int wr = w >> 2;                 // 0..1
    const int wc = w & 3;                  // 0..3

    f32x4 acc[8][4];
    #pragma unroll
    for (int i = 0; i < 8; ++i)
        #pragma unroll
        for (int j = 0; j < 4; ++j) acc[i][j] = (f32x4){0.f, 0.f, 0.f, 0.f};

    // staging: thread tid covers row (c*128 + tid>>2), 16B unit (tid&3), pre-swizzled source
    const int srow = tid >> 2;
    const int su = ((tid & 3) ^ ((tid >> 3) & 3)) * 8;   // element offset within BK
    const bf16* gA0 = A + (size_t)(m0 + srow) * lda + su;
    const bf16* gA1 = gA0 + (size_t)128 * lda;
    const bf16* gB0 = B + (size_t)(n0 + srow) * ldb + su;
    const bf16* gB1 = gB0 + (size_t)128 * ldb;
    const int wofs = w * 512;              // wave-uniform LDS stage base (elems)

    const int qx = (quad ^ ((l15 >> 1) & 3)) * 8;        // swizzled read unit (elems)
    const int arow = wr * 128 + l15;
    const int brow = wc * 64 + l15;
    const int nk = K >> 5;

    auto STAGE = [&](int s) {
        bf16* base = lds + (s & 3) * 16384;
        const size_t ko = (size_t)s * 32;
        gll16(gA0 + ko, base + wofs);
        gll16(gA1 + ko, base + 4096 + wofs);
        gll16(gB0 + ko, base + 8192 + wofs);
        gll16(gB1 + ko, base + 12288 + wofs);
    };
    STAGE(0); STAGE(1); STAGE(2);          // 12 loads in flight

    for (int t = 0; t < nk; ++t) {
        const int rem = nk - 1 - t;
        if (rem >= 2)      asm volatile("s_waitcnt vmcnt(8)" ::: "memory");
        else if (rem == 1) asm volatile("s_waitcnt vmcnt(4)" ::: "memory");
        else               asm volatile("s_waitcnt vmcnt(0)" ::: "memory");
        __builtin_amdgcn_s_barrier();
        asm volatile("" ::: "memory");     // keep LDS reads below the barrier
        const bf16* bufA = lds + (t & 3) * 16384;
        const bf16* bufB = bufA + 8192;
        short8 af[8], bfr[4];
        #pragma unroll
        for (int i = 0; i < 8; ++i)
            af[i] = *reinterpret_cast<const short8*>(bufA + (arow + i * 16) * 32 + qx);
        #pragma unroll
        for (int j = 0; j < 4; ++j)
            bfr[j] = *reinterpret_cast<const short8*>(bufB + (brow + j * 16) * 32 + qx);
        if (t + 3 < nk) STAGE(t + 3);      // into slot (t+3)&3 == (t-1)&3, freed by this barrier
        #pragma unroll
        for (int i = 0; i < 8; ++i)
            #pragma unroll
            for (int j = 0; j < 4; ++j)
                acc[i][j] = __builtin_amdgcn_mfma_f32_16x16x32_bf16(af[i], bfr[j], acc[i][j], 0, 0, 0);
    }

    // epilogue: C/D layout col = lane&15, row = quad*4 + reg  [verified m89/m91]
    const int rbase = m0 + wr * 128 + quad * 4;
    if constexpr (EPI == 2) {
        float* C = (float*)Cout;
        #pragma unroll
        for (int i = 0; i < 8; ++i)
            #pragma unroll
            for (int r = 0; r < 4; ++r) {
                const size_t ro = (size_t)(rbase + i * 16 + r) * N;
                #pragma unroll
                for (int j = 0; j < 4; ++j) {
                    const int c2 = n0 + wc * 64 + j * 16 + l15;
                    C[ro + c2] = acc[i][j][r] + aux[ro + c2];
                }
            }
    } else {  // EPI == 3: split bf16 store, cols [0,2048)->Cout else Cout2, both ldc=2048
        bf16* C = (bf16*)((n0 < 2048) ? Cout : Cout2);
        const int cb = (n0 & 2047) + wc * 64;
        #pragma unroll
        for (int i = 0; i < 8; ++i)
            #pragma unroll
            for (int r = 0; r < 4; ++r) {
                const size_t ro = (size_t)(rbase + i * 16 + r) * 2048;
                #pragma unroll
                for (int j = 0; j < 4; ++j)
                    C[ro + cb + j * 16 + l15] = f2b(acc[i][j][r]);
            }
    }
    (void)aux;
}

// ---------------- x_proj split-K combine: p0+p1 -> dtr (bf16) + bcbuf (f32) ----------------
__global__ __launch_bounds__(256) void combine_xproj(const float* __restrict__ p0,
                                                     const float* __restrict__ p1,
                                                     bf16* __restrict__ dtr,
                                                     float* __restrict__ bcbuf) {
    const int idx = blockIdx.x * 256 + threadIdx.x;   // over NROWS*128
    const int c = idx & 127;
    const int row = idx >> 7;
    const float v = p0[idx] + p1[idx];
    if (c < 64) dtr[(size_t)row * 64 + c] = f2b(v);
    else if (c < 96) bcbuf[(size_t)row * 32 + (c - 64)] = v;
}

// ============== chunked selective scan (3 passes), NC = chunk count ==============
__device__ __forceinline__ bool pow_ok(const float* a) {
    bool ok = true;
    #pragma unroll
    for (int s = 1; s < 16; ++s) {
        const float t = a[0] * (s + 1);
        ok = ok && (fabsf(a[s] - t) <= 1e-4f * fabsf(t) + 1e-6f);
    }
    return ok;
}

template <int NC>
__global__ __launch_bounds__(256) void scan_passA(const bf16* __restrict__ dt,
                                                  const bf16* __restrict__ xc,
                                                  const float* __restrict__ bcbuf,
                                                  const float* __restrict__ A_log,
                                                  float* __restrict__ hend,
                                                  float* __restrict__ sumdt) {
    constexpr int LC = SEQ_N / NC;
    __shared__ __align__(16) float sbc[LC * 32];
    const int e = blockIdx.x * 256 + threadIdx.x;
    const int c = blockIdx.y;
    const int b = blockIdx.z;
    const size_t rbase = (size_t)b * SEQ_N + (size_t)c * LC;
    #pragma unroll
    for (int idx = threadIdx.x; idx < LC * 8; idx += 256)
        reinterpret_cast<float4*>(sbc)[idx] =
            reinterpret_cast<const float4*>(bcbuf + rbase * 32)[idx];
    float a[16], h[16];
    #pragma unroll
    for (int s = 0; s < 16; ++s) {
        a[s] = -__expf(A_log[e * 16 + s]);
        h[s] = 0.f;
    }
    const bool pw = pow_ok(a);
    float sd = 0.f;
    __syncthreads();
    // manual 2-stage row pipeline: preload row i+1's globals before row i's serial chain
    float dtv = b2f(dt[rbase * DINNER + e]);
    float xv  = b2f(xc[rbase * DINNER + e]);
    for (int i = 0; i < LC; ++i) {
        float ndtv = 0.f, nxv = 0.f;
        if (i + 1 < LC) {
            const size_t rn = rbase + i + 1;
            ndtv = b2f(dt[rn * DINNER + e]);
            nxv  = b2f(xc[rn * DINNER + e]);
        }
        const float cdx = dtv * xv;
        const float4* bp = reinterpret_cast<const float4*>(sbc + i * 32);
        float Bv[16];
        *reinterpret_cast<float4*>(&Bv[0])  = bp[0];
        *reinterpret_cast<float4*>(&Bv[4])  = bp[1];
        *reinterpret_cast<float4*>(&Bv[8])  = bp[2];
        *reinterpret_cast<float4*>(&Bv[12]) = bp[3];
        sd += dtv;
        if (pw) {
            const float e1 = __expf(dtv * a[0]);
            float dAp = 1.f;
            #pragma unroll
            for (int s = 0; s < 16; ++s) {
                dAp *= e1;
                h[s] = fmaf(h[s], dAp, cdx * Bv[s]);
            }
        } else {
            #pragma unroll
            for (int s = 0; s < 16; ++s) {
                const float dA = __expf(dtv * a[s]);
                h[s] = fmaf(h[s], dA, cdx * Bv[s]);
            }
        }
        dtv = ndtv; xv = nxv;
    }
    const size_t o = ((size_t)b * NC + c) * DINNER + e;
    #pragma unroll
    for (int s = 0; s < 16; s += 4) {
        float4 v = {h[s], h[s + 1], h[s + 2], h[s + 3]};
        *reinterpret_cast<float4*>(hend + o * 16 + s) = v;
    }
    sumdt[o] = sd;
}

template <int NC>
__global__ __launch_bounds__(256) void scan_passB(float* hstate,
                                                  const float* __restrict__ sumdt,
                                                  const float* __restrict__ A_log) {
    const int g = blockIdx.x * 256 + threadIdx.x;
    const int s = g & 15;
    const int e = (g >> 4) & (DINNER - 1);
    const int b = g >> 15;
    const float a = -__expf(A_log[e * 16 + s]);
    float H = 0.f;
    for (int c = 0; c < NC; ++c) {
        const size_t o = ((size_t)b * NC + c) * DINNER + e;
        const float he = hstate[o * 16 + s];
        const float sd = sumdt[o];
        hstate[o * 16 + s] = H;
        H = fmaf(H, __expf(a * sd), he);
    }
}

template <int NC>
__global__ __launch_bounds__(256) void scan_passC(const bf16* dt,
                                                  const bf16* __restrict__ xc,
                                                  const bf16* __restrict__ z,
                                                  const float* __restrict__ bcbuf,
                                                  const float* __restrict__ A_log,
                                                  const float* __restrict__ D_skip,
                                                  const float* __restrict__ hinit,
                                                  bf16* y) {
    constexpr int LC = SEQ_N / NC;
    __shared__ __align__(16) float sbc[LC * 32];
    const int e = blockIdx.x * 256 + threadIdx.x;
    const int c = blockIdx.y;
    const int b = blockIdx.z;
    const size_t rbase = (size_t)b * SEQ_N + (size_t)c * LC;
    #pragma unroll
    for (int idx = threadIdx.x; idx < LC * 8; idx += 256)
        reinterpret_cast<float4*>(sbc)[idx] =
            reinterpret_cast<const float4*>(bcbuf + rbase * 32)[idx];
    float a[16], h[16];
    #pragma unroll
    for (int s = 0; s < 16; ++s) a[s] = -__expf(A_log[e * 16 + s]);
    const bool pw = pow_ok(a);
    const float dsk = D_skip[e];
    const size_t o = ((size_t)b * NC + c) * DINNER + e;
    #pragma unroll
    for (int s = 0; s < 16; s += 4) {
        float4 v = *reinterpret_cast<const float4*>(hinit + o * 16 + s);
        h[s] = v.x; h[s + 1] = v.y; h[s + 2] = v.z; h[s + 3] = v.w;
    }
    __syncthreads();
    // manual 2-stage row pipeline (dt/y alias the same buffer: loads for row i+1 are
    // placed in program order BEFORE row i's y store is reached -- safe, same thread,
    // different rows; gives the serial chain a full row of load latency cover)
    float dtv = b2f(dt[rbase * DINNER + e]);
    float xv  = b2f(xc[rbase * DINNER + e]);
    float zv  = b2f(z[rbase * DINNER + e]);
    for (int i = 0; i < LC; ++i) {
        const size_t row = rbase + i;
        float ndtv = 0.f, nxv = 0.f, nzv = 0.f;
        if (i + 1 < LC) {
            const size_t rn = row + 1;
            ndtv = b2f(dt[rn * DINNER + e]);
            nxv  = b2f(xc[rn * DINNER + e]);
            nzv  = b2f(z[rn * DINNER + e]);
        }
        const float cdx = dtv * xv;
        const float4* bp = reinterpret_cast<const float4*>(sbc + i * 32);
        float Bv[16], Cv[16];
        *reinterpret_cast<float4*>(&Bv[0])  = bp[0];
        *reinterpret_cast<float4*>(&Bv[4])  = bp[1];
        *reinterpret_cast<float4*>(&Bv[8])  = bp[2];
        *reinterpret_cast<float4*>(&Bv[12]) = bp[3];
        *reinterpret_cast<float4*>(&Cv[0])  = bp[4];
        *reinterpret_cast<float4*>(&Cv[4])  = bp[5];
        *reinterpret_cast<float4*>(&Cv[8])  = bp[6];
        *reinterpret_cast<float4*>(&Cv[12]) = bp[7];
        float yv = 0.f;
        if (pw) {
            const float e1 = __expf(dtv * a[0]);
            float dAp = 1.f;
            #pragma unroll
            for (int s = 0; s < 16; ++s) {
                dAp *= e1;
                h[s] = fmaf(h[s], dAp, cdx * Bv[s]);
                yv = fmaf(h[s], Cv[s], yv);
            }
        } else {
            #pragma unroll
            for (int s = 0; s < 16; ++s) {
                const float dA = __expf(dtv * a[s]);
                h[s] = fmaf(h[s], dA, cdx * Bv[s]);
                yv = fmaf(h[s], Cv[s], yv);
            }
        }
        const float g = (yv + dsk * xv) * (zv / (1.f + __expf(-zv)));
        y[row * DINNER + e] = f2b(g);
        dtv = ndtv; xv = nxv; zv = nzv;
    }
}

extern "C" void kernel_launch(void* const* d_in, const int* in_sizes, int n_in,
                              void* d_out, int out_size, void* d_ws, size_t ws_size,
                              hipStream_t stream) {
    const float* x         = (const float*)d_in[0];
    const float* in_proj_w = (const float*)d_in[1];
    const float* conv_w    = (const float*)d_in[2];
    const float* conv_b    = (const float*)d_in[3];
    const float* x_proj_w  = (const float*)d_in[4];
    const float* dt_proj_w = (const float*)d_in[5];
    const float* dt_proj_b = (const float*)d_in[6];
    const float* A_log     = (const float*)d_in[7];
    const float* D_skip    = (const float*)d_in[8];
    const float* out_proj_w= (const float*)d_in[9];
    float* out = (float*)d_out;

    // workspace layout (bytes)
    char* ws = (char*)d_ws;
    bf16*  xcraw = (bf16*)(ws + 0);            // 67,108,864  [-> dtb -> y]
    bf16*  xc    = (bf16*)(ws + 67108864);     // 67,108,864  [u lives here first]
    bf16*  dtr   = (bf16*)(ws + 134217728);    //  2,097,152  [16384 x 64 bf16]
    float* bcbuf = (float*)(ws + 136314880);   //  2,097,152  [16384 x 32 f32]
    bf16*  w_in  = (bf16*)(ws + 140509184);    //  8,388,608
    bf16*  w_xp  = (bf16*)(ws + 148897792);    //    524,288  [padded to 128 x 2048]
    bf16*  w_dt  = (bf16*)(ws + 149422080);    //    262,144
    bf16*  w_out = (bf16*)(ws + 149684224);    //  4,194,304
    float* hend  = (float*)(ws + 153878528);   // NC=64: 33,554,432 | NC=32: 16,777,216
    bf16*  u     = xc;
    bf16*  dtb   = xcraw;
    bf16*  yb    = dtb;
    bf16*  zbuf  = (bf16*)d_out;               // z in d_out; overwritten by out-proj last
    // x_proj split-K partials alias hend (dead until scanA): 2 x 8 MB f32
    float* xp_p0 = hend;
    float* xp_p1 = hend + (size_t)NROWS * 128;

    const bool big = (ws_size >= 189530112ULL);   // room for NC=64 layout?
    float* sumdt = (float*)(ws + (big ? 187432960 : 170655744));

    // 0+1. weight converts (x4 vectorized) + rmsnorm (single launch)
    prep_kernel<<<NROWS + CVT_TOTAL / 1024, 256, 0, stream>>>(
        x, u, in_proj_w, w_in, x_proj_w, w_xp, dt_proj_w, w_dt, out_proj_w, w_out);
    // 2. xz = u @ in_proj^T, split-stored: cols [0,2048)->xcraw, [2048,4096)->zbuf
    mfma_gemm256<3><<<dim3((NROWS / 256) * (4096 / 256)), 512, 0, stream>>>(
        u, DMODEL, w_in, DMODEL, xcraw, zbuf, nullptr, 4096, DMODEL);
    // 3. conv + silu -> xc (overwrites u; reads only xcraw)
    conv_silu4_kernel<<<(NROWS * DINNER) / 1024, 256, 0, stream>>>(xcraw, conv_w, conv_b, xc);
    // 4. x_proj split-K=2: partials (f32, N=128) -> combine into dtr + bcbuf
    mfma_gemm<5><<<dim3(NROWS / 128, 1, 2), 256, 0, stream>>>(
        xc, DINNER, w_xp, DINNER, xp_p0, nullptr, nullptr, 128, DINNER / 2);
    combine_xproj<<<(NROWS * 128) / 256, 256, 0, stream>>>(xp_p0, xp_p1, dtr, bcbuf);
    // 5. dt = softplus(dtr @ dt_proj^T + b)  [16384, 2048]  (over xcraw)
    mfma_gemm<1><<<dim3(NROWS / 128, DINNER / 128), 256, 0, stream>>>(
        dtr, DTRANK, w_dt, DTRANK, dtb, nullptr, dt_proj_b, DINNER, DTRANK);
    // 6. chunked selective scan, NC=64 (r1/r6 A-B: NC=32 halves scan occupancy, +13 us total)
    if (big) {
        scan_passA<64><<<dim3(DINNER / 256, 64, BATCH_N), 256, 0, stream>>>(
            dtb, xc, bcbuf, A_log, hend, sumdt);
        scan_passB<64><<<(BATCH_N * DINNER * DSTATE) / 256, 256, 0, stream>>>(hend, sumdt, A_log);
        scan_passC<64><<<dim3(DINNER / 256, 64, BATCH_N), 256, 0, stream>>>(
            dtb, xc, zbuf, bcbuf, A_log, D_skip, hend, yb);
    } else {
        scan_passA<32><<<dim3(DINNER / 256, 32, BATCH_N), 256, 0, stream>>>(
            dtb, xc, bcbuf, A_log, hend, sumdt);
        scan_passB<32><<<(BATCH_N * DINNER * DSTATE) / 256, 256, 0, stream>>>(hend, sumdt, A_log);
        scan_passC<32><<<dim3(DINNER / 256, 32, BATCH_N), 256, 0, stream>>>(
            dtb, xc, zbuf, bcbuf, A_log, D_skip, hend, yb);
    }
    // 7. out = x + y @ out_proj^T  [16384, 1024]
    mfma_gemm256<2><<<dim3((NROWS / 256) * (DMODEL / 256)), 512, 0, stream>>>(
        yb, DINNER, w_out, DINNER, out, nullptr, x, DMODEL, DINNER);
    (void)in_sizes; (void)n_in; (void)out_size;
}